// Round 13
// baseline (304.481 us; speedup 1.0000x reference)
//
#include <hip/hip_runtime.h>
#include <cmath>

// ---------------------------------------------------------------- types
typedef __bf16 bf16x8 __attribute__((ext_vector_type(8)));
typedef __bf16 bf16x4 __attribute__((ext_vector_type(4)));
typedef float  floatx4 __attribute__((ext_vector_type(4)));

#define LN_EPS 1e-5f
#define INV_TEMP 0.125f   // 1/sqrt(64)

// B=32 S=512 D=512 H=8 DK=DV=64 DFF=2048, M = B*S = 16384
static const int Mrows = 16384;

__device__ __forceinline__ void gload_lds16(const void* g, void* l) {
  __builtin_amdgcn_global_load_lds(
      (const __attribute__((address_space(1))) void*)g,
      (__attribute__((address_space(3))) void*)l, 16, 0, 0);
}

// ---------------------------------------------------------------- fused prep: x->bf16 + 6 weight transposes
__global__ __launch_bounds__(256) void prep_kernel(const float* __restrict__ x, __bf16* __restrict__ xb,
                                                   const float* __restrict__ wq, const float* __restrict__ wk,
                                                   const float* __restrict__ wv, const float* __restrict__ wo,
                                                   const float* __restrict__ wff1, const float* __restrict__ wff2,
                                                   __bf16* __restrict__ tq, __bf16* __restrict__ tk,
                                                   __bf16* __restrict__ tv, __bf16* __restrict__ to_,
                                                   __bf16* __restrict__ tff1, __bf16* __restrict__ tff2) {
  const int bid = blockIdx.x, tid = threadIdx.x;
  if (bid < 8192) {
    int i = bid * 256 + tid;
    float4 v = ((const float4*)x)[i];
    __bf16* d = xb + i * 4;
    d[0] = (__bf16)v.x; d[1] = (__bf16)v.y; d[2] = (__bf16)v.z; d[3] = (__bf16)v.w;
    return;
  }
  __shared__ __bf16 til[64][72];
  int t = bid - 8192;
  const float* src; __bf16* dst; int R, C, bx, by;
  if (t < 256) {
    int w = t >> 6, tt = t & 63;
    const float* srcs[4] = {wq, wk, wv, wo};
    __bf16* dsts[4] = {tq, tk, tv, to_};
    src = srcs[w]; dst = dsts[w]; R = 512; C = 512; bx = tt & 7; by = tt >> 3;
  } else if (t < 512) {
    int tt = t - 256;
    src = wff1; dst = tff1; R = 512; C = 2048; bx = tt & 31; by = tt >> 5;
  } else {
    int tt = t - 512;
    src = wff2; dst = tff2; R = 2048; C = 512; bx = tt & 7; by = tt >> 3;
  }
  const float* s = src + (size_t)(by * 64) * C + bx * 64;
  int r = tid >> 4, c4 = (tid & 15) * 4;
  for (int p = 0; p < 4; ++p) {
    int rr = r + p * 16;
    float4 v = *(const float4*)(s + (size_t)rr * C + c4);
    til[c4 + 0][rr] = (__bf16)v.x;
    til[c4 + 1][rr] = (__bf16)v.y;
    til[c4 + 2][rr] = (__bf16)v.z;
    til[c4 + 3][rr] = (__bf16)v.w;
  }
  __syncthreads();
  __bf16* d = dst + (size_t)(bx * 64) * R + by * 64;
  int orow = tid >> 3, oc8 = (tid & 7) * 8;
  for (int p = 0; p < 2; ++p) {
    int rr = orow + p * 32;
    *(bf16x8*)(d + (size_t)rr * R + oc8) = *(const bf16x8*)(&til[rr][oc8]);
  }
}

// ---------------------------------------------------------------- 128x256 8-wave GEMM, 3-slot K-half ring
// (unchanged from R11 - passing, FFN1 43.5us; used for QKV / FFN1)
template <int EPI, int NBN, int NDIM, int KDIM, int NKS>
__global__ __launch_bounds__(512, 4) void gemm256(const __bf16* __restrict__ A,
                                                  const __bf16* __restrict__ Bt,
                                                  __bf16* __restrict__ Cv,
                                                  const float* __restrict__ bias,
                                                  float* __restrict__ norms,
                                                  __bf16* __restrict__ vtg) {
  __shared__ __align__(16) char smem[73728];
  const int tid = threadIdx.x;
  const int wave = tid >> 6, lane = tid & 63;
  const int l15 = lane & 15, quad = lane >> 4;
  const int wm = wave >> 2, wn = wave & 3;

  constexpr int NBM = Mrows / 128;          // 128
  constexpr int NBLK = NBM * NBN * NKS;
  constexpr int KS = KDIM / NKS;
  constexpr int NTH = KS / 32;

  int id = blockIdx.x;
  int t = (id & 7) * (NBLK >> 3) + (id >> 3);   // XCD-chunked bijective swizzle
  const int ks = t / (NBM * NBN);
  t -= ks * (NBM * NBN);
  const int nblk = t % NBN, mblk = t / NBN;
  const int m0 = mblk * 128, n0 = nblk * 256;
  const __bf16* Ab = A + (size_t)ks * KS;
  const __bf16* Bb = Bt + (size_t)ks * KS;
  __bf16* Cw = Cv + (size_t)ks * Mrows * NDIM;
  (void)bias;

  // stage mapping: 24 chunks (A 0-7, B 8-23), 3 per wave; pair-line layout.
  const int l3 = lane >> 3, s_ = lane & 7;
  const int rl = l3 * 2 + (s_ >> 2);
  const int ksw = (s_ & 3) ^ (l3 & 3);
  const __bf16* sb[3];
  int ldo[3];
#pragma unroll
  for (int j = 0; j < 3; ++j) {
    int c = wave * 3 + j;
    int isB = c >= 8 ? 1 : 0;
    int cc = c - isB * 8;
    int row = cc * 16 + rl;
    sb[j] = (isB ? Bb + (size_t)(n0 + row) * KDIM
                 : Ab + (size_t)(m0 + row) * KDIM) + ksw * 8;
    ldo[j] = isB * 8192 + cc * 1024 + lane * 16;
  }

  const int lrt = (l15 >> 1) * 128 + (((l15 & 1) * 4 + (quad ^ ((l15 >> 1) & 3))) * 16);

  floatx4 zero = {0.f, 0.f, 0.f, 0.f};
  floatx4 acc[4][4];
#pragma unroll
  for (int i = 0; i < 4; ++i)
#pragma unroll
    for (int j = 0; j < 4; ++j) acc[i][j] = zero;

#define STAGEH(h, slotIdx)                                                   \
  {                                                                          \
    _Pragma("unroll") for (int j = 0; j < 3; ++j)                            \
        gload_lds16(sb[j] + (h) * 32, smem + (slotIdx) * 24576 + ldo[j]);    \
  }

#define READMFMA(slotIdx)                                                    \
  {                                                                          \
    const char* slotp = smem + (slotIdx) * 24576;                            \
    bf16x8 aF[4], bF[4];                                                     \
    _Pragma("unroll") for (int i = 0; i < 4; ++i)                            \
      aF[i] = *(const bf16x8*)(slotp + (wm * 4 + i) * 1024 + lrt);           \
    _Pragma("unroll") for (int j = 0; j < 4; ++j)                            \
      bF[j] = *(const bf16x8*)(slotp + 8192 + (wn * 4 + j) * 1024 + lrt);    \
    DOSTAGE_HOOK;                                                            \
    __builtin_amdgcn_s_setprio(1);                                           \
    _Pragma("unroll") for (int i = 0; i < 4; ++i)                            \
      _Pragma("unroll") for (int j = 0; j < 4; ++j)                          \
        acc[i][j] = __builtin_amdgcn_mfma_f32_16x16x32_bf16(aF[i], bF[j],    \
                                                            acc[i][j], 0, 0, 0); \
    __builtin_amdgcn_s_setprio(0);                                           \
  }

  STAGEH(0, 0);
  STAGEH(1, 1);

  int sl = 0;
  for (int h = 0; h < NTH - 1; ++h) {
    asm volatile("s_waitcnt vmcnt(3)" ::: "memory");
    __builtin_amdgcn_s_barrier();
    int st = (sl == 0) ? 2 : sl - 1;          // (sl+2)%3
    if (h < NTH - 2) {
#define DOSTAGE_HOOK STAGEH(h + 2, st)
      READMFMA(sl);
#undef DOSTAGE_HOOK
    } else {
#define DOSTAGE_HOOK
      READMFMA(sl);
#undef DOSTAGE_HOOK
    }
    sl = (sl == 2) ? 0 : sl + 1;
  }
  asm volatile("s_waitcnt vmcnt(0)" ::: "memory");
  __builtin_amdgcn_s_barrier();
#define DOSTAGE_HOOK
  READMFMA(sl);
#undef DOSTAGE_HOOK

#undef STAGEH
#undef READMFMA

  if (EPI == 4) {
    int head_global = (n0 + wn * 64) >> 6;
    int kind = head_global >> 3;
    if (kind < 2) {
      int h = head_global & 7;
#pragma unroll
      for (int ii = 0; ii < 4; ++ii)
#pragma unroll
        for (int r = 0; r < 4; ++r) {
          float sq = 0.f;
#pragma unroll
          for (int jj = 0; jj < 4; ++jj) {
            float v = acc[ii][jj][r];
            sq += v * v;
          }
          for (int m = 1; m < 16; m <<= 1) sq += __shfl_xor(sq, m, 64);
          if (l15 == 0) {
            int arow = m0 + wm * 64 + ii * 16 + quad * 4 + r;
            int bb = arow >> 9, ss = arow & 511;
            norms[kind * 131072 + ((bb << 3) + h) * 512 + ss] = rsqrtf(sq);
          }
        }
    } else {
      const int PADT = 72;
      __bf16* Ct = (__bf16*)smem;
      int bb = m0 >> 9, s0r = m0 & 511;
#pragma unroll
      for (int hh = 0; hh < 2; ++hh) {
        __builtin_amdgcn_s_barrier();
        if (wm == hh) {
#pragma unroll
          for (int ii = 0; ii < 4; ++ii)
#pragma unroll
            for (int jj = 0; jj < 4; ++jj) {
              bf16x4 pk;
#pragma unroll
              for (int r = 0; r < 4; ++r) pk[r] = (__bf16)acc[ii][jj][r];
              *(bf16x4*)(Ct + (wn * 64 + jj * 16 + l15) * PADT + ii * 16 + quad * 4) = pk;
            }
        }
        __builtin_amdgcn_s_barrier();
#pragma unroll
        for (int p = 0; p < 4; ++p) {
          int c = p * 64 + (tid >> 3);
          int s8 = (tid & 7) * 8;
          int h = ((n0 + c) >> 6) & 7, d = c & 63;
          *(bf16x8*)(vtg + ((size_t)(((bb << 3) + h) * 64 + d)) * 512 + s0r + hh * 64 + s8) =
              *(const bf16x8*)(Ct + c * PADT + s8);
        }
      }
      return;
    }
  }

  const int PADC = 264;
  __bf16* Cs = (__bf16*)smem;
  float bv[4];
  if (EPI == 2) {
#pragma unroll
    for (int j = 0; j < 4; ++j) bv[j] = bias[n0 + wn * 64 + j * 16 + l15];
  }
#pragma unroll
  for (int hh = 0; hh < 2; ++hh) {
    __builtin_amdgcn_s_barrier();
    if (wm == hh) {
#pragma unroll
      for (int i = 0; i < 4; ++i)
#pragma unroll
        for (int j = 0; j < 4; ++j)
#pragma unroll
          for (int r = 0; r < 4; ++r) {
            float v = acc[i][j][r];
            if (EPI == 2) {
              v += bv[j];
              v = v > 0.f ? v : 0.f;
            }
            Cs[(i * 16 + quad * 4 + r) * PADC + wn * 64 + j * 16 + l15] = (__bf16)v;
          }
    }
    __builtin_amdgcn_s_barrier();
#pragma unroll
    for (int p = 0; p < 4; ++p) {
      int rowl = p * 16 + (tid >> 5);
      int c8 = (tid & 31) * 8;
      *(bf16x8*)(Cw + (size_t)(m0 + hh * 64 + rowl) * NDIM + n0 + c8) =
          *(const bf16x8*)(Cs + rowl * PADC + c8);
    }
  }
}

// ---------------------------------------------------------------- 64x512 GEMM with FUSED residual+LayerNorm
// NEW: tile 64 rows x FULL N=512 -> block owns entire LN rows; fuses residual
// (+bias) + LayerNorm into the epilogue. Eliminates the w_o/FFN2 partial
// write+read roundtrips and both resid_ln dispatches (~96MB HBM + 2 launches).
// K-loop = verbatim gemm256 ring (3-slot, pair-line conflict-free chunks,
// counted vmcnt, no lgkm drain). 8 waves, wave w = rows[0,64) x cols[w*64,+64).
// Chunks: A 4 (rows 0-63), B 32 (cols 0-511). Waves 0-3 stage 4 B + 1 A = 5;
// waves 4-7 stage 4 B. Wave-uniform vmcnt(5)/vmcnt(4) ladder.
// LDS: 3 x 36KB = 108KB -> 1 block/CU; grid 256 = one full round.
// RESF32: residual from f32 (x) else bf16 (h1b). OUTF32: write f32 (out) else
// bf16 (h1b). HASB: add bias (b_ff2) before LN.
template <bool RESF32, bool OUTF32, bool HASB, int KDIM>
__global__ __launch_bounds__(512, 2) void gemmLN(const __bf16* __restrict__ A,
                                                 const __bf16* __restrict__ Bt,
                                                 const float* __restrict__ resf,
                                                 const __bf16* __restrict__ resb,
                                                 const float* __restrict__ bias,
                                                 const float* __restrict__ g,
                                                 const float* __restrict__ be,
                                                 float* __restrict__ outf,
                                                 __bf16* __restrict__ outb) {
  __shared__ __align__(16) char smem[110592];   // 3 x 36KB slots
  const int tid = threadIdx.x;
  const int wave = tid >> 6, lane = tid & 63;
  const int l15 = lane & 15, quad = lane >> 4;

  constexpr int NBLK = Mrows / 64;   // 256
  constexpr int NTH = KDIM / 32;

  int id = blockIdx.x;
  int t = (id & 7) * (NBLK >> 3) + (id >> 3);   // XCD-chunked bijective swizzle
  const int m0 = t * 64;

  // stage mapping (pair-line layout, verbatim):
  const int l3 = lane >> 3, s_ = lane & 7;
  const int rl = l3 * 2 + (s_ >> 2);
  const int ksw = (s_ & 3) ^ (l3 & 3);
  const __bf16* sbB[4];
  int ldoB[4];
#pragma unroll
  for (int j = 0; j < 4; ++j) {
    int c = wave * 4 + j;                       // B chunk 0..31 (C-col rows)
    sbB[j] = Bt + (size_t)(c * 16 + rl) * KDIM + ksw * 8;
    ldoB[j] = 4096 + c * 1024 + lane * 16;
  }
  const __bf16* sbA = A + (size_t)(m0 + wave * 16 + rl) * KDIM + ksw * 8;  // waves 0-3
  const int ldoA = wave * 1024 + lane * 16;

  const int lrt = (l15 >> 1) * 128 + (((l15 & 1) * 4 + (quad ^ ((l15 >> 1) & 3))) * 16);

  floatx4 zero = {0.f, 0.f, 0.f, 0.f};
  floatx4 acc[4][4];
#pragma unroll
  for (int i = 0; i < 4; ++i)
#pragma unroll
    for (int j = 0; j < 4; ++j) acc[i][j] = zero;

#define STAGELN(h, slotIdx)                                                  \
  {                                                                          \
    _Pragma("unroll") for (int j = 0; j < 4; ++j)                            \
        gload_lds16(sbB[j] + (h) * 32, smem + (slotIdx) * 36864 + ldoB[j]);  \
    if (wave < 4)                                                            \
      gload_lds16(sbA + (h) * 32, smem + (slotIdx) * 36864 + ldoA);          \
  }

#define VMWAITLN()                                                           \
  {                                                                          \
    if (wave < 4) asm volatile("s_waitcnt vmcnt(5)" ::: "memory");           \
    else          asm volatile("s_waitcnt vmcnt(4)" ::: "memory");           \
  }

#define READMFMALN(slotIdx)                                                  \
  {                                                                          \
    const char* slotp = smem + (slotIdx) * 36864;                            \
    bf16x8 aF[4], bF[4];                                                     \
    _Pragma("unroll") for (int i = 0; i < 4; ++i)                            \
      aF[i] = *(const bf16x8*)(slotp + i * 1024 + lrt);                      \
    _Pragma("unroll") for (int j = 0; j < 4; ++j)                            \
      bF[j] = *(const bf16x8*)(slotp + 4096 + (wave * 4 + j) * 1024 + lrt);  \
    DOSTAGE_HOOK;                                                            \
    __builtin_amdgcn_s_setprio(1);                                           \
    _Pragma("unroll") for (int i = 0; i < 4; ++i)                            \
      _Pragma("unroll") for (int j = 0; j < 4; ++j)                          \
        acc[i][j] = __builtin_amdgcn_mfma_f32_16x16x32_bf16(aF[i], bF[j],    \
                                                            acc[i][j], 0, 0, 0); \
    __builtin_amdgcn_s_setprio(0);                                           \
  }

  STAGELN(0, 0);
  STAGELN(1, 1);

  int sl = 0;
  for (int h = 0; h < NTH - 1; ++h) {
    VMWAITLN();
    __builtin_amdgcn_s_barrier();
    int st = (sl == 0) ? 2 : sl - 1;          // (sl+2)%3
    if (h < NTH - 2) {
#define DOSTAGE_HOOK STAGELN(h + 2, st)
      READMFMALN(sl);
#undef DOSTAGE_HOOK
    } else {
#define DOSTAGE_HOOK
      READMFMALN(sl);
#undef DOSTAGE_HOOK
    }
    sl = (sl == 2) ? 0 : sl + 1;
  }
  asm volatile("s_waitcnt vmcnt(0)" ::: "memory");
  __builtin_amdgcn_s_barrier();
#define DOSTAGE_HOOK
  READMFMALN(sl);
#undef DOSTAGE_HOOK

#undef STAGELN
#undef VMWAITLN
#undef READMFMALN

  // ---------- fused residual (+bias) + LayerNorm epilogue ----------
  __syncthreads();                         // protect smem reuse (slot overlays)
  float* redS = (float*)smem;              // [8][64]
  float* redQ = (float*)(smem + 2048);     // [8][64]
  float* mstd = (float*)(smem + 4096);     // [0..63]=mean, [64..127]=rstd

  float bv[4], gv[4], bev[4];
#pragma unroll
  for (int j = 0; j < 4; ++j) {
    int col = wave * 64 + j * 16 + l15;
    bv[j] = HASB ? bias[col] : 0.f;
    gv[j] = g[col];
    bev[j] = be[col];
  }

#pragma unroll
  for (int i = 0; i < 4; ++i)
#pragma unroll
    for (int r = 0; r < 4; ++r) {
      int rowl = i * 16 + quad * 4 + r;
      size_t grow = (size_t)(m0 + rowl) * 512;
      float s = 0.f, q = 0.f;
#pragma unroll
      for (int j = 0; j < 4; ++j) {
        int col = wave * 64 + j * 16 + l15;
        float rv = RESF32 ? resf[grow + col] : (float)resb[grow + col];
        float v = acc[i][j][r] + bv[j] + rv;
        acc[i][j][r] = v;
        s += v;
        q += v * v;
      }
      for (int m = 1; m < 16; m <<= 1) {
        s += __shfl_xor(s, m, 64);
        q += __shfl_xor(q, m, 64);
      }
      if (l15 == 0) {
        redS[wave * 64 + rowl] = s;
        redQ[wave * 64 + rowl] = q;
      }
    }
  __syncthreads();
  if (tid < 64) {
    float s = 0.f, q = 0.f;
#pragma unroll
    for (int w = 0; w < 8; ++w) {
      s += redS[w * 64 + tid];
      q += redQ[w * 64 + tid];
    }
    float mean = s * (1.f / 512.f);
    float var = q * (1.f / 512.f) - mean * mean;
    mstd[tid] = mean;
    mstd[64 + tid] = rsqrtf(var + LN_EPS);
  }
  __syncthreads();
#pragma unroll
  for (int i = 0; i < 4; ++i)
#pragma unroll
    for (int r = 0; r < 4; ++r) {
      int rowl = i * 16 + quad * 4 + r;
      size_t grow = (size_t)(m0 + rowl) * 512;
      float mean = mstd[rowl], rstd = mstd[64 + rowl];
#pragma unroll
      for (int j = 0; j < 4; ++j) {
        int col = wave * 64 + j * 16 + l15;
        float o = (acc[i][j][r] - mean) * rstd * gv[j] + bev[j];
        if (OUTF32) outf[grow + col] = o;
        else        outb[grow + col] = (__bf16)o;
      }
    }
}

// ---------------------------------------------------------------- attention (2-slot K/V ring, hoisted fragments)
// (unchanged from round 10/11 - passing)
__global__ __launch_bounds__(256) void attn_kernel(const __bf16* __restrict__ qkv,
                                                   const __bf16* __restrict__ vtg,
                                                   const float* __restrict__ norms,
                                                   __bf16* __restrict__ out) {
  __shared__ __align__(16) __bf16 KV[2][8192];   // [slot][K 8KB | V 8KB] = 32KB
  __shared__ __align__(16) __bf16 P2[4][16 * 72];
  const int tid = threadIdx.x, wave = tid >> 6, lane = tid & 63;
  const int l15 = lane & 15, quad = lane >> 4;
  const int bh = blockIdx.x & 255;
  const int qq = blockIdx.x >> 8;
  const int b = bh >> 3, h = bh & 7;
  const int qbase = qq * 128 + wave * 32;
  const int rs = lane >> 3;
  const int swz_st = ((lane & 7) ^ rs) * 8;
  const int s7 = l15 & 7;

  const __bf16* Qb = qkv + (size_t)(b * 512) * 1536 + h * 64;
  const __bf16* Kb = Qb + 512;
  const __bf16* Vtb = vtg + (size_t)bh * 32768;
  const float* nkinv = norms + 131072 + bh * 512;
  const float* nqinv = norms + bh * 512;
  __bf16* Pw = P2[wave];

  bf16x8 aq[2][2];
  float cq[2];
  for (int ch = 0; ch < 2; ++ch) {
    int qrow = qbase + ch * 16;
    aq[ch][0] = *(const bf16x8*)(Qb + (size_t)(qrow + l15) * 1536 + quad * 8);
    aq[ch][1] = *(const bf16x8*)(Qb + (size_t)(qrow + l15) * 1536 + 32 + quad * 8);
    cq[ch] = nqinv[qrow + l15] * INV_TEMP;
  }

  floatx4 zero = {0.f, 0.f, 0.f, 0.f};
  floatx4 o[2][4];
  float lsum[2] = {0.f, 0.f};
  for (int ch = 0; ch < 2; ++ch)
    for (int jd = 0; jd < 4; ++jd) o[ch][jd] = zero;

#define STAGEKV(kt, s)                                                        \
  {                                                                           \
    int s0q = (kt) * 64;                                                      \
    _Pragma("unroll") for (int c = 0; c < 4; ++c) {                           \
      int g = wave * 4 + c;                                                   \
      const __bf16* src;                                                      \
      __bf16* dst;                                                            \
      if (g < 8) {                                                            \
        int sk = g * 8 + rs;                                                  \
        src = Kb + (size_t)(s0q + sk) * 1536 + swz_st;                        \
        dst = KV[s] + g * 512;                                                \
      } else {                                                                \
        int g2 = g - 8;                                                       \
        int dd = g2 * 8 + rs;                                                 \
        src = Vtb + (size_t)dd * 512 + s0q + swz_st;                          \
        dst = KV[s] + 4096 + g2 * 512;                                        \
      }                                                                       \
      gload_lds16(src, dst + lane * 8);                                       \
    }                                                                         \
  }

  STAGEKV(0, 0);

  for (int kt = 0; kt < 8; ++kt) {
    int s0 = kt * 64;
    int sl = kt & 1;
    asm volatile("s_waitcnt vmcnt(0)" ::: "memory");
    __builtin_amdgcn_s_barrier();
    if (kt < 7) STAGEKV(kt + 1, sl ^ 1);
    const __bf16* Ks = KV[sl];
    const __bf16* Vs = KV[sl] + 4096;

    floatx4 nk[4];
#pragma unroll
    for (int j = 0; j < 4; ++j)
      nk[j] = *(const floatx4*)(nkinv + s0 + j * 16 + quad * 4);

    bf16x8 kf[4][2];
#pragma unroll
    for (int j = 0; j < 4; ++j) {
      int r64 = (j * 16 + l15) * 64;
      kf[j][0] = *(const bf16x8*)(Ks + r64 + ((quad ^ s7) * 8));
      kf[j][1] = *(const bf16x8*)(Ks + r64 + (((4 + quad) ^ s7) * 8));
    }

    floatx4 z[2][4];
    __builtin_amdgcn_s_setprio(1);
#pragma unroll
    for (int ch = 0; ch < 2; ++ch)
#pragma unroll
      for (int j = 0; j < 4; ++j) {
        floatx4 zz = zero;
        zz = __builtin_amdgcn_mfma_f32_16x16x32_bf16(kf[j][0], aq[ch][0], zz, 0, 0, 0);
        zz = __builtin_amdgcn_mfma_f32_16x16x32_bf16(kf[j][1], aq[ch][1], zz, 0, 0, 0);
        z[ch][j] = zz;
      }
    __builtin_amdgcn_s_setprio(0);

    bf16x8 vf[4][2];
#pragma unroll
    for (int jd = 0; jd < 4; ++jd) {
      int r64 = (jd * 16 + l15) * 64;
      vf[jd][0] = *(const bf16x8*)(Vs + r64 + ((quad ^ s7) * 8));
      vf[jd][1] = *(const bf16x8*)(Vs + r64 + (((4 + quad) ^ s7) * 8));
    }

#pragma unroll
    for (int ch = 0; ch < 2; ++ch) {
#pragma unroll
      for (int j = 0; j < 4; ++j) {
        bf16x4 pk;
#pragma unroll
        for (int r = 0; r < 4; ++r) {
          float p = __expf(z[ch][j][r] * cq[ch] * nk[j][r]);
          lsum[ch] += p;
          pk[r] = (__bf16)p;
        }
        *(bf16x4*)(Pw + l15 * 72 + j * 16 + quad * 4) = pk;
      }
      bf16x8 ap0 = *(const bf16x8*)(Pw + l15 * 72 + quad * 8);
      bf16x8 ap1 = *(const bf16x8*)(Pw + l15 * 72 + 32 + quad * 8);
      __builtin_amdgcn_s_setprio(1);
#pragma unroll
      for (int jd = 0; jd < 4; ++jd) {
        o[ch][jd] = __builtin_amdgcn_mfma_f32_16x16x32_bf16(vf[jd][0], ap0, o[ch][jd], 0, 0, 0);
        o[ch][jd] = __builtin_amdgcn_mfma_f32_16x16x32_bf16(vf[jd][1], ap1, o[ch][jd], 0, 0, 0);
      }
      __builtin_amdgcn_s_setprio(0);
    }
  }
#undef STAGEKV

  for (int ch = 0; ch < 2; ++ch) {
    float s = lsum[ch];
    s += __shfl_xor(s, 16, 64);
    s += __shfl_xor(s, 32, 64);
    float inv = __builtin_amdgcn_rcpf(s);
    int q = qbase + ch * 16 + l15;
    __bf16* op = out + (size_t)(b * 512 + q) * 512 + h * 64;
    for (int jd = 0; jd < 4; ++jd) {
      bf16x4 pk;
      for (int r = 0; r < 4; ++r) pk[r] = (__bf16)(o[ch][jd][r] * inv);
      *(bf16x4*)(op + jd * 16 + quad * 4) = pk;
    }
  }
}

// ---------------------------------------------------------------- launcher
extern "C" void kernel_launch(void* const* d_in, const int* in_sizes, int n_in,
                              void* d_out, int out_size, void* d_ws, size_t ws_size,
                              hipStream_t stream) {
  const float* x     = (const float*)d_in[0];
  const float* w_q   = (const float*)d_in[1];
  const float* w_k   = (const float*)d_in[2];
  const float* w_v   = (const float*)d_in[3];
  const float* w_o   = (const float*)d_in[4];
  const float* w_ff1 = (const float*)d_in[5];
  const float* b_ff1 = (const float*)d_in[6];
  const float* w_ff2 = (const float*)d_in[7];
  const float* b_ff2 = (const float*)d_in[8];
  const float* g1    = (const float*)d_in[9];
  const float* b1    = (const float*)d_in[10];
  const float* g2    = (const float*)d_in[11];
  const float* b2    = (const float*)d_in[12];
  float* out = (float*)d_out;

  char* ws = (char*)d_ws;
  size_t off = 0;
  auto alloc = [&](size_t bytes) -> void* {
    void* p = ws + off;
    off += (bytes + 255) & ~(size_t)255;
    return p;
  };
  __bf16* xb     = (__bf16*)alloc((size_t)Mrows * 512 * 2);
  __bf16* wt_qkv = (__bf16*)alloc((size_t)1536 * 512 * 2);
  __bf16* wt_o   = (__bf16*)alloc((size_t)512 * 512 * 2);
  __bf16* wt_ff1 = (__bf16*)alloc((size_t)2048 * 512 * 2);
  __bf16* wt_ff2 = (__bf16*)alloc((size_t)512 * 2048 * 2);
  __bf16* qkv    = (__bf16*)alloc((size_t)Mrows * 1536 * 2);
  float*  norms  = (float*)alloc((size_t)262144 * 4);
  __bf16* attn   = (__bf16*)alloc((size_t)Mrows * 512 * 2);
  __bf16* h1b    = (__bf16*)alloc((size_t)Mrows * 512 * 2);
  __bf16* mid    = (__bf16*)alloc((size_t)Mrows * 2048 * 2);
  __bf16* vtg    = mid;            // alias: vtg dead before FFN1 writes mid

  prep_kernel<<<8960, 256, 0, stream>>>(x, xb, w_q, w_k, w_v, w_o, w_ff1, w_ff2,
                                        wt_qkv, wt_qkv + 512 * 512, wt_qkv + 2 * 512 * 512,
                                        wt_o, wt_ff1, wt_ff2);

  // QKV (fused inverse norms + V-transpose into vtg), grid 128x6=768
  gemm256<4, 6, 1536, 512, 1><<<dim3(768), 512, 0, stream>>>(xb, wt_qkv, qkv, nullptr,
                                                             norms, vtg);
  attn_kernel<<<dim3(1024), 256, 0, stream>>>(qkv, vtg, norms, attn);
  // w_o proj with FUSED residual(x)+LN1 -> h1b (bf16), grid 256
  gemmLN<true, false, false, 512><<<dim3(256), 512, 0, stream>>>(attn, wt_o, x, nullptr,
                                                                 nullptr, g1, b1,
                                                                 nullptr, h1b);
  // FFN1 (+bias, relu): grid 128x8=1024
  gemm256<2, 8, 2048, 512, 1><<<dim3(1024), 512, 0, stream>>>(h1b, wt_ff1, mid, b_ff1,
                                                              nullptr, nullptr);
  // FFN2 with FUSED bias+residual(h1b)+LN2 -> out (f32), grid 256
  gemmLN<false, true, true, 2048><<<dim3(256), 512, 0, stream>>>(mid, wt_ff2, nullptr, h1b,
                                                                 b_ff2, g2, b2,
                                                                 out, nullptr);
}